// Round 3
// baseline (46.373 us; speedup 1.0000x reference)
//
#include <hip/hip_runtime.h>
#include <stdint.h>
#include <math.h>

#define NLVL 16
#define NPTS 131072
#define CHUNK 256          // points per block
#define NXCD 8

struct Meta {
  int scales[NLVL];
  int offsets[NLVL];      // element offsets (max ~6.1M, fits int32)
  unsigned int T;
  int start_hash;
  double invT;
};

// h < 2^38, T ~ 2^19. (double)h is exact; q off by at most +-1, fixed up.
__device__ __forceinline__ int fastmod(uint64_t h, unsigned int T, double invT) {
  uint64_t q = (uint64_t)((double)h * invT);
  long long r = (long long)(h - q * (uint64_t)T);
  if (r < 0) r += (long long)T;
  else if (r >= (long long)T) r -= (long long)T;
  return (int)r;
}

// 8 corner indices (level offset folded in) + fractional offsets for level l.
// Bit-matches fp32 reference: corner index = (int)(fx + corner_f32).
__device__ __forceinline__ void level_idx(
    int l, float xn, float yn, float zn, const Meta& m,
    int* __restrict__ idx, float* __restrict__ o)
{
#pragma clang fp contract(off)
  const float sf = (float)m.scales[l];
  const float fx = xn * sf, fy = yn * sf, fz = zn * sf;
  const int ix0 = (int)fx,          iy0 = (int)fy,          iz0 = (int)fz;
  const int ix1 = (int)(fx + 1.0f), iy1 = (int)(fy + 1.0f), iz1 = (int)(fz + 1.0f);
  o[0] = fx - (float)ix0; o[1] = fy - (float)iy0; o[2] = fz - (float)iz0;
  const int base = m.offsets[l];

  if (l < m.start_hash) {
    const int sp1 = m.scales[l] + 1;
    const int sq  = sp1 * sp1;
    const int ax0 = ix0 * sq,  ax1 = ix1 * sq;
    const int ay0 = iy0 * sp1, ay1 = iy1 * sp1;
    idx[0] = base + ax0 + ay0 + iz0;
    idx[1] = base + ax0 + ay0 + iz1;
    idx[2] = base + ax0 + ay1 + iz0;
    idx[3] = base + ax0 + ay1 + iz1;
    idx[4] = base + ax1 + ay0 + iz0;
    idx[5] = base + ax1 + ay0 + iz1;
    idx[6] = base + ax1 + ay1 + iz0;
    idx[7] = base + ax1 + ay1 + iz1;
  } else {
    const uint64_t hx0 = (uint64_t)ix0;
    const uint64_t hx1 = (uint64_t)ix1;          // = hx0 + 1
    const uint64_t hy0 = (uint64_t)iy0 * 19349663ull;
    const uint64_t hy1 = hy0 + 19349663ull;      // iy1 == iy0 + 1 always
    const uint64_t hz0 = (uint64_t)iz0 * 83492791ull;
    const uint64_t hz1 = hz0 + 83492791ull;
    idx[0] = base + fastmod(hx0 ^ hy0 ^ hz0, m.T, m.invT);
    idx[1] = base + fastmod(hx0 ^ hy0 ^ hz1, m.T, m.invT);
    idx[2] = base + fastmod(hx0 ^ hy1 ^ hz0, m.T, m.invT);
    idx[3] = base + fastmod(hx0 ^ hy1 ^ hz1, m.T, m.invT);
    idx[4] = base + fastmod(hx1 ^ hy0 ^ hz0, m.T, m.invT);
    idx[5] = base + fastmod(hx1 ^ hy0 ^ hz1, m.T, m.invT);
    idx[6] = base + fastmod(hx1 ^ hy1 ^ hz0, m.T, m.invT);
    idx[7] = base + fastmod(hx1 ^ hy1 ^ hz1, m.T, m.invT);
  }
}

__device__ __forceinline__ void accum8(
    const float2* __restrict__ v, const float* __restrict__ o,
    float& a0, float& a1)
{
#pragma clang fp contract(off)
  const float wx[2] = {1.0f - o[0], o[0]};
  const float wy[2] = {1.0f - o[1], o[1]};
  const float wz[2] = {1.0f - o[2], o[2]};
  a0 = 0.0f; a1 = 0.0f;
#pragma unroll
  for (int c = 0; c < 8; ++c) {
    const float w = (wx[(c >> 2) & 1] * wy[(c >> 1) & 1]) * wz[c & 1];
    a0 += w * v[c].x;
    a1 += w * v[c].y;
  }
}

// Block = 256 threads = 256 points for one level-pair {g, g+8}.
// Grid = 512 chunks x 8 groups, blockIdx = chunk*8 + group so that the
// default round-robin workgroup->XCD dispatch puts group g on XCD g.
// Each XCD's L2 then only sees levels {g, g+8}: 4.2-8.4 MB working set
// instead of 48.8 MB.
__global__ __launch_bounds__(256) void hashgrid_fwd(
    const float* __restrict__ xyz,
    const float* __restrict__ wb,
    const float* __restrict__ data,
    float* __restrict__ out,
    Meta meta)
{
#pragma clang fp contract(off)
  const int c     = threadIdx.x;
  const int group = blockIdx.x & (NXCD - 1);
  const int chunk = blockIdx.x >> 3;
  const int pbase = chunk * CHUNK;

  // Stage this chunk's xyz (256 pts x 3 floats = 768 floats) via float4.
  __shared__ float sxyz[CHUNK * 3];
  if (c < CHUNK * 3 / 4) {
    reinterpret_cast<float4*>(sxyz)[c] =
        reinterpret_cast<const float4*>(xyz + pbase * 3)[c];
  }
  __syncthreads();

  const float bx0 = wb[0], by0 = wb[1], bz0 = wb[2];
  const float bx1 = wb[3], by1 = wb[4], bz1 = wb[5];
  const float denom = fmaxf(fmaxf(bx1 - bx0, by1 - by0), bz1 - bz0) + 1e-6f;

  float px = sxyz[c * 3 + 0], py = sxyz[c * 3 + 1], pz = sxyz[c * 3 + 2];
  px = fminf(fmaxf(px, bx0), bx1);
  py = fminf(fmaxf(py, by0), by1);
  pz = fminf(fmaxf(pz, bz0), bz1);
  const float xn = (px - bx0) / denom;
  const float yn = (py - by0) / denom;
  const float zn = (pz - bz0) / denom;

  const int lA = group, lB = group + 8;
  int idxA[8], idxB[8];
  float oA[3], oB[3];
  level_idx(lA, xn, yn, zn, meta, idxA, oA);
  level_idx(lB, xn, yn, zn, meta, idxB, oB);

  const float2* __restrict__ dp = (const float2*)data;
  float2 vA[8], vB[8];
#pragma unroll
  for (int k = 0; k < 8; ++k) vA[k] = dp[idxA[k]];
#pragma unroll
  for (int k = 0; k < 8; ++k) vB[k] = dp[idxB[k]];

  float2 rA, rB;
  accum8(vA, oA, rA.x, rA.y);
  accum8(vB, oB, rB.x, rB.y);

  // out is [N][16 levels][2 floats]; this block owns level columns lA, lB.
  float2* __restrict__ o2 = reinterpret_cast<float2*>(out);
  const int pt = pbase + c;
  o2[pt * NLVL + lA] = rA;
  o2[pt * NLVL + lB] = rB;
}

static bool isprime_ll(long long v) {
  if (v < 2) return false;
  for (long long i = 2; i * i <= v; ++i)
    if (v % i == 0) return false;
  return true;
}

extern "C" void kernel_launch(void* const* d_in, const int* in_sizes, int n_in,
                              void* d_out, int out_size, void* d_ws, size_t ws_size,
                              hipStream_t stream) {
  (void)in_sizes; (void)n_in; (void)d_ws; (void)ws_size; (void)out_size;

  Meta m;
  long long T = 1LL << 19;
  while (!isprime_ll(T)) ++T;
  const double b = pow(2048.0 / 16.0, 1.0 / 15.0);
  long long off = 0;
  int sh = -1;
  for (int i = 0; i < NLVL; ++i) {
    const int res = (int)(16.0 * pow(b, (double)i));   // matches int(16 * b**i)
    m.scales[i] = res;
    m.offsets[i] = (int)off;
    long long nn = (long long)(res + 1) * (res + 1) * (res + 1);
    if (nn > T) { if (sh < 0) sh = i; nn = T; }
    off += nn;
  }
  m.T = (unsigned int)T;
  m.start_hash = (sh < 0) ? NLVL : sh;
  m.invT = 1.0 / (double)T;

  const float* xyz  = (const float*)d_in[0];
  const float* wbp  = (const float*)d_in[1];
  const float* data = (const float*)d_in[2];
  float* out = (float*)d_out;

  hipLaunchKernelGGL(hashgrid_fwd, dim3((NPTS / CHUNK) * NXCD), dim3(256), 0,
                     stream, xyz, wbp, data, out, m);
}

// Round 4
// 32.538 us; speedup vs baseline: 1.4252x; 1.4252x over previous
//
#include <hip/hip_runtime.h>
#include <stdint.h>
#include <math.h>

#define NLVL 16
#define NPTS 131072
#define BPTS 64            // points per block
#define NTHR 256           // 4 waves

struct Meta {
  int scales[NLVL];
  int offsets[NLVL];      // element offsets (max ~6.1M, fits int32)
  unsigned int T;
  int start_hash;
  double invT;
};

// h < 2^38, T ~ 2^19. (double)h is exact; q off by at most +-1, fixed up.
__device__ __forceinline__ int fastmod(uint64_t h, unsigned int T, double invT) {
  uint64_t q = (uint64_t)((double)h * invT);
  long long r = (long long)(h - q * (uint64_t)T);
  if (r < 0) r += (long long)T;
  else if (r >= (long long)T) r -= (long long)T;
  return (int)r;
}

// 8 corner indices (level offset folded in) + fractional offsets for level l.
// Bit-matches fp32 reference: corner index = (int)(fx + corner_f32).
__device__ __forceinline__ void level_idx(
    int l, float xn, float yn, float zn, const Meta& m,
    int* __restrict__ idx, float* __restrict__ o)
{
#pragma clang fp contract(off)
  const float sf = (float)m.scales[l];
  const float fx = xn * sf, fy = yn * sf, fz = zn * sf;
  const int ix0 = (int)fx,          iy0 = (int)fy,          iz0 = (int)fz;
  const int ix1 = (int)(fx + 1.0f), iy1 = (int)(fy + 1.0f), iz1 = (int)(fz + 1.0f);
  o[0] = fx - (float)ix0; o[1] = fy - (float)iy0; o[2] = fz - (float)iz0;
  const int base = m.offsets[l];

  if (l < m.start_hash) {
    const int sp1 = m.scales[l] + 1;
    const int sq  = sp1 * sp1;
    const int ax0 = ix0 * sq,  ax1 = ix1 * sq;
    const int ay0 = iy0 * sp1, ay1 = iy1 * sp1;
    idx[0] = base + ax0 + ay0 + iz0;
    idx[1] = base + ax0 + ay0 + iz1;
    idx[2] = base + ax0 + ay1 + iz0;
    idx[3] = base + ax0 + ay1 + iz1;
    idx[4] = base + ax1 + ay0 + iz0;
    idx[5] = base + ax1 + ay0 + iz1;
    idx[6] = base + ax1 + ay1 + iz0;
    idx[7] = base + ax1 + ay1 + iz1;
  } else {
    const uint64_t hx0 = (uint64_t)ix0;
    const uint64_t hx1 = (uint64_t)ix1;          // = hx0 + 1
    const uint64_t hy0 = (uint64_t)iy0 * 19349663ull;
    const uint64_t hy1 = hy0 + 19349663ull;      // iy1 == iy0 + 1 always
    const uint64_t hz0 = (uint64_t)iz0 * 83492791ull;
    const uint64_t hz1 = hz0 + 83492791ull;
    idx[0] = base + fastmod(hx0 ^ hy0 ^ hz0, m.T, m.invT);
    idx[1] = base + fastmod(hx0 ^ hy0 ^ hz1, m.T, m.invT);
    idx[2] = base + fastmod(hx0 ^ hy1 ^ hz0, m.T, m.invT);
    idx[3] = base + fastmod(hx0 ^ hy1 ^ hz1, m.T, m.invT);
    idx[4] = base + fastmod(hx1 ^ hy0 ^ hz0, m.T, m.invT);
    idx[5] = base + fastmod(hx1 ^ hy0 ^ hz1, m.T, m.invT);
    idx[6] = base + fastmod(hx1 ^ hy1 ^ hz0, m.T, m.invT);
    idx[7] = base + fastmod(hx1 ^ hy1 ^ hz1, m.T, m.invT);
  }
}

// Block = 256 threads = 4 waves; block owns 64 points.
// Wave w computes levels {w, w+4, w+8, w+12} (1 dense + 3 hashed: balanced).
// Lane <-> point through a block-local spatial counting sort so that
// duplicate/nearby points occupy adjacent lanes and their gathers coalesce.
__global__ __launch_bounds__(NTHR) void hashgrid_fwd(
    const float* __restrict__ xyz,
    const float* __restrict__ wb,
    const float* __restrict__ data,
    float* __restrict__ out,
    Meta meta)
{
#pragma clang fp contract(off)
  const int t    = threadIdx.x;
  const int wave = t >> 6;
  const int lane = t & 63;
  const int pbase = blockIdx.x * BPTS;

  __shared__ float  sxyz[BPTS * 3];      // 768 B
  __shared__ int    hist[64];            // res-4 cell histogram
  __shared__ int    sidx[BPTS];          // sorted -> original point slot
  __shared__ float2 tile[BPTS][NLVL + 1];// +1 pad: 4-way instead of 64-way

  if (t < 48)
    reinterpret_cast<float4*>(sxyz)[t] =
        reinterpret_cast<const float4*>(xyz + pbase * 3)[t];
  if (t < 64) hist[t] = 0;
  __syncthreads();

  const float bx0 = wb[0], by0 = wb[1], bz0 = wb[2];
  const float bx1 = wb[3], by1 = wb[4], bz1 = wb[5];
  const float denom = fmaxf(fmaxf(bx1 - bx0, by1 - by0), bz1 - bz0) + 1e-6f;

  // ---- Phase 1: key per original point, histogram (wave 0 only) ----
  int key = 0;
  if (t < 64) {
    float px = sxyz[t * 3 + 0], py = sxyz[t * 3 + 1], pz = sxyz[t * 3 + 2];
    px = fminf(fmaxf(px, bx0), bx1);
    py = fminf(fmaxf(py, by0), by1);
    pz = fminf(fmaxf(pz, bz0), bz1);
    const float xn = (px - bx0) / denom;
    const float yn = (py - by0) / denom;
    const float zn = (pz - bz0) / denom;
    const int kx = min((int)(xn * 4.0f), 3);
    const int ky = min((int)(yn * 4.0f), 3);
    const int kz = min((int)(zn * 4.0f), 3);
    key = kx * 16 + ky * 4 + kz;
    atomicAdd(&hist[key], 1);
  }
  __syncthreads();

  // ---- Phase 2: inclusive scan of 64 bins (wave 0 shuffle scan) ----
  if (t < 64) {
    int v = hist[t];
#pragma unroll
    for (int d = 1; d < 64; d <<= 1) {
      int u = __shfl_up(v, d, 64);
      if (lane >= d) v += u;
    }
    hist[t] = v;   // inclusive prefix (bin end offset)
  }
  __syncthreads();

  // ---- Phase 3: scatter into sorted order (fill each bin from its end) ----
  if (t < 64) {
    const int pos = atomicSub(&hist[key], 1) - 1;
    sidx[pos] = t;
  }
  __syncthreads();

  // ---- Phase 4: compute; lane processes sorted point ----
  const int p = sidx[lane];
  float px = sxyz[p * 3 + 0], py = sxyz[p * 3 + 1], pz = sxyz[p * 3 + 2];
  px = fminf(fmaxf(px, bx0), bx1);
  py = fminf(fmaxf(py, by0), by1);
  pz = fminf(fmaxf(pz, bz0), bz1);
  const float xn = (px - bx0) / denom;
  const float yn = (py - by0) / denom;
  const float zn = (pz - bz0) / denom;

  const float2* __restrict__ dp = (const float2*)data;

#pragma unroll 2
  for (int s = 0; s < 4; ++s) {
    const int l = wave + 4 * s;
    int idx[8];
    float o[3];
    level_idx(l, xn, yn, zn, meta, idx, o);

    float2 v[8];
#pragma unroll
    for (int k = 0; k < 8; ++k) v[k] = dp[idx[k]];

    const float wx[2] = {1.0f - o[0], o[0]};
    const float wy[2] = {1.0f - o[1], o[1]};
    const float wz[2] = {1.0f - o[2], o[2]};
    float a0 = 0.0f, a1 = 0.0f;
#pragma unroll
    for (int c = 0; c < 8; ++c) {
      const float w = (wx[(c >> 2) & 1] * wy[(c >> 1) & 1]) * wz[c & 1];
      a0 += w * v[c].x;
      a1 += w * v[c].y;
    }
    tile[p][l] = make_float2(a0, a1);
  }
  __syncthreads();

  // ---- Phase 5: coalesced float4 store in original order ----
#pragma unroll
  for (int it = 0; it < 2; ++it) {
    const int idx = t + it * NTHR;       // 0..511 float4s
    const int pp = idx >> 3;             // point
    const int q  = idx & 7;              // float4 within point (levels 2q,2q+1)
    const float2 e0 = tile[pp][2 * q];
    const float2 e1 = tile[pp][2 * q + 1];
    reinterpret_cast<float4*>(out)[(pbase + pp) * 8 + q] =
        make_float4(e0.x, e0.y, e1.x, e1.y);
  }
}

static bool isprime_ll(long long v) {
  if (v < 2) return false;
  for (long long i = 2; i * i <= v; ++i)
    if (v % i == 0) return false;
  return true;
}

extern "C" void kernel_launch(void* const* d_in, const int* in_sizes, int n_in,
                              void* d_out, int out_size, void* d_ws, size_t ws_size,
                              hipStream_t stream) {
  (void)in_sizes; (void)n_in; (void)d_ws; (void)ws_size; (void)out_size;

  Meta m;
  long long T = 1LL << 19;
  while (!isprime_ll(T)) ++T;
  const double b = pow(2048.0 / 16.0, 1.0 / 15.0);
  long long off = 0;
  int sh = -1;
  for (int i = 0; i < NLVL; ++i) {
    const int res = (int)(16.0 * pow(b, (double)i));   // matches int(16 * b**i)
    m.scales[i] = res;
    m.offsets[i] = (int)off;
    long long nn = (long long)(res + 1) * (res + 1) * (res + 1);
    if (nn > T) { if (sh < 0) sh = i; nn = T; }
    off += nn;
  }
  m.T = (unsigned int)T;
  m.start_hash = (sh < 0) ? NLVL : sh;
  m.invT = 1.0 / (double)T;

  const float* xyz  = (const float*)d_in[0];
  const float* wbp  = (const float*)d_in[1];
  const float* data = (const float*)d_in[2];
  float* out = (float*)d_out;

  hipLaunchKernelGGL(hashgrid_fwd, dim3(NPTS / BPTS), dim3(NTHR), 0, stream,
                     xyz, wbp, data, out, m);
}